// Round 7
// baseline (2396.494 us; speedup 1.0000x reference)
//
#include <hip/hip_runtime.h>
#include <hip/hip_cooperative_groups.h>
#include <math.h>

namespace cg = cooperative_groups;

#define HIDDEN 16
#define CIN 5
#define BB 8
#define TT 12
#define HH 256
#define WW 256
#define TX 32
#define TY 8
#define HALO_X 34
#define HALO_Y 10
#define NPX (HALO_X * HALO_Y)   // 340 staged pixels
#define STRIDE 40               // shorts per px row: 80 B -> max 2-way bank aliasing (free)
#define NBLK 512                // persistent blocks = 2 per CU (co-residency with slack)
#define SLOTS 4                 // tiles per block per step

typedef __attribute__((ext_vector_type(8))) short bf16x8;
typedef __attribute__((ext_vector_type(4))) float floatx4;

__device__ __forceinline__ unsigned short f2bf(float f) {   // RNE fp32->bf16
    unsigned int u = __float_as_uint(f);
    u += 0x7fffu + ((u >> 16) & 1u);
    return (unsigned short)(u >> 16);
}
__device__ __forceinline__ float bf2f(unsigned short s) {
    return __uint_as_float(((unsigned int)s) << 16);
}
__device__ __forceinline__ float fast_sigmoid(float x) { return 1.0f / (1.0f + __expf(-x)); }
__device__ __forceinline__ float fast_tanh(float x) {
    float e2 = __expf(-2.0f * fabsf(x));
    float t = (1.0f - e2) / (1.0f + e2);
    return copysignf(t, x);
}

// Pack W_cell [64][21][3][3] into B-fragment layout for mfma_f32_16x16x32_bf16:
// Wfrag[tap][gate][lane][j]; lane holds B[k=(lane>>4)*8+j][col=lane&15].
// k-order: 0..15 = h units (ci_ref 5+k), 16..20 = x chans, 21..31 = 0.
__global__ void prep_w_kernel(const float* __restrict__ Wc,
                              unsigned short* __restrict__ Wfrag) {
    int i = blockIdx.x * 256 + threadIdx.x;
    if (i >= 9 * 4 * 64 * 8) return;
    int j    = i & 7;
    int lane = (i >> 3) & 63;
    int g    = (i >> 9) & 3;
    int tap  = i >> 11;
    int k    = ((lane >> 4) << 3) + j;
    int col  = lane & 15;
    int o    = g * 16 + col;
    float w  = 0.0f;
    if (k < 21) {
        int ci_ref = (k < 16) ? (5 + k) : (k - 16);
        w = Wc[(o * 21 + ci_ref) * 9 + tap];
    }
    Wfrag[i] = f2bf(w);
}

// One-time x repack: planar fp32 [b][t][c][y][x] -> channel-last bf16 [b][t][y][x][8]
__global__ void prep_x_kernel(const float* __restrict__ x,
                              unsigned short* __restrict__ xp) {
    size_t n = (size_t)blockIdx.x * 256 + threadIdx.x;
    const size_t TOTPX = (size_t)BB * TT * HH * WW;
    if (n >= TOTPX) return;
    size_t bt  = n / (size_t)(HH * WW);
    size_t pix = n - bt * (size_t)(HH * WW);
    const float* src = x + bt * (size_t)CIN * HH * WW + pix;
    unsigned short v[8];
    #pragma unroll
    for (int c = 0; c < CIN; ++c) v[c] = f2bf(src[(size_t)c * HH * WW]);
    v[5] = 0; v[6] = 0; v[7] = 0;
    *(uint4*)&xp[n * 8] = *(const uint4*)v;
}

// Stage one 32x8 tile (+halo) into LDS: [px][k] bf16, k = 16 h + 5 x + pad.
__device__ __forceinline__ void stage_tile(unsigned short* __restrict__ dst,
                                           int tid, int bb, int y0, int x0,
                                           int t, int first,
                                           const unsigned short* __restrict__ xp,
                                           const unsigned short* __restrict__ h_rd) {
    for (int i = tid; i < NPX; i += 256) {
        int ly = i / HALO_X;
        int lx = i - ly * HALO_X;
        int gy = y0 + ly - 1;
        int gx = x0 + lx - 1;
        bool inb = (gy >= 0 && gy < HH && gx >= 0 && gx < WW);
        unsigned short* row = &dst[i * STRIDE];
        uint4 z = {0, 0, 0, 0};
        if (inb && !first) {
            size_t hb = ((size_t)bb * HH * WW + (size_t)gy * WW + gx) * HIDDEN;
            *(uint4*)&row[0] = *(const uint4*)&h_rd[hb];
            *(uint4*)&row[8] = *(const uint4*)&h_rd[hb + 8];
        } else {
            *(uint4*)&row[0] = z;
            *(uint4*)&row[8] = z;
        }
        if (inb) {
            size_t xb = (((size_t)bb * TT + t) * (size_t)(HH * WW)
                         + (size_t)gy * WW + gx) * 8;
            *(uint4*)&row[16] = *(const uint4*)&xp[xb];
        } else {
            *(uint4*)&row[16] = z;
        }
        *(uint4*)&row[24] = z;
    }
}

// Conv (implicit GEMM, 9 taps) + fused gates; creg[16] carries c-state.
__device__ __forceinline__ void compute_slot(const unsigned short* __restrict__ buf,
                                             const unsigned short* __restrict__ Wfrag,
                                             const float* __restrict__ bg,
                                             const int* __restrict__ abase,
                                             int bb, int y0, int x0,
                                             int lane, int wave, int u, int quad,
                                             float* __restrict__ creg,
                                             unsigned short* __restrict__ h_wr) {
    #pragma unroll 1
    for (int half = 0; half < 2; ++half) {
        floatx4 acc[2][4];
        #pragma unroll
        for (int mh = 0; mh < 2; ++mh)
            #pragma unroll
            for (int g = 0; g < 4; ++g)
                acc[mh][g] = (floatx4){bg[g], bg[g], bg[g], bg[g]};

        #pragma unroll 3
        for (int tap = 0; tap < 9; ++tap) {
            int ky = tap / 3;
            int kx = tap - ky * 3;
            int toff = (ky * HALO_X + kx) * STRIDE;
            bf16x8 bfr[4];
            #pragma unroll
            for (int g = 0; g < 4; ++g)
                bfr[g] = *(const bf16x8*)&Wfrag[(size_t)((tap * 4 + g) * 64 + lane) * 8];
            #pragma unroll
            for (int mh = 0; mh < 2; ++mh) {
                bf16x8 af = *(const bf16x8*)&buf[abase[half * 2 + mh] + toff];
                #pragma unroll
                for (int g = 0; g < 4; ++g)
                    acc[mh][g] = __builtin_amdgcn_mfma_f32_16x16x32_bf16(
                        af, bfr[g], acc[mh][g], 0, 0, 0);
            }
        }

        #pragma unroll
        for (int mh = 0; mh < 2; ++mh) {
            int ml = half * 2 + mh;
            int m  = wave + ml * 4;
            int my = m >> 1;
            int mx = (m & 1) << 4;
            int py = y0 + my;
            #pragma unroll
            for (int r = 0; r < 4; ++r) {
                int pxx = x0 + mx + quad * 4 + r;
                size_t idx = ((size_t)bb * HH * WW + (size_t)py * WW + pxx) * HIDDEN + u;
                float ig = fast_sigmoid(acc[mh][0][r]);
                float fg = fast_sigmoid(acc[mh][1][r]);
                float og = fast_sigmoid(acc[mh][2][r]);
                float gg = fast_tanh(acc[mh][3][r]);
                float c_new = fg * creg[ml * 4 + r] + ig * gg;
                creg[ml * 4 + r] = c_new;
                h_wr[idx] = f2bf(og * fast_tanh(c_new));
            }
        }
    }
}

// Persistent ConvLSTM: all 12 steps, c in registers, double-buffered slot staging.
__global__ __launch_bounds__(256, 2)
void convlstm_persistent_kernel(const unsigned short* __restrict__ xp,
                                unsigned short* __restrict__ h_a,
                                unsigned short* __restrict__ h_b,
                                const unsigned short* __restrict__ Wfrag,
                                const float* __restrict__ bias) {
    cg::grid_group grid = cg::this_grid();
    __shared__ unsigned short tile[2][NPX * STRIDE];   // 54.4 KB

    const int tid  = threadIdx.x;
    const int lane = tid & 63;
    const int wave = tid >> 6;
    const int u    = lane & 15;
    const int quad = lane >> 4;

    float bg[4];
    #pragma unroll
    for (int g = 0; g < 4; ++g) bg[g] = bias[g * 16 + u];

    int abase[4];
    #pragma unroll
    for (int ml = 0; ml < 4; ++ml) {
        int m  = wave + ml * 4;
        int my = m >> 1;
        int mx = (m & 1) << 4;
        abase[ml] = (my * HALO_X + mx + u) * STRIDE + quad * 8;
    }

    // tile coords per slot
    int sy0[SLOTS], sx0[SLOTS], sbb[SLOTS];
    #pragma unroll
    for (int s = 0; s < SLOTS; ++s) {
        int tileid = (int)blockIdx.x + s * NBLK;
        sbb[s] = tileid >> 8;
        int rm = tileid & 255;
        sy0[s] = (rm >> 3) * TY;
        sx0[s] = (rm & 7) * TX;
    }

    float creg[SLOTS][16];
    #pragma unroll
    for (int s = 0; s < SLOTS; ++s)
        #pragma unroll
        for (int j = 0; j < 16; ++j) creg[s][j] = 0.0f;

    #pragma unroll 1
    for (int t = 0; t < TT; ++t) {
        const unsigned short* h_rd = (t & 1) ? h_a : h_b;
        unsigned short*       h_wr = (t & 1) ? h_b : h_a;
        const int first = (t == 0);

        stage_tile(tile[0], tid, sbb[0], sy0[0], sx0[0], t, first, xp, h_rd);
        #pragma unroll 1
        for (int s = 0; s < SLOTS; ++s) {
            __syncthreads();
            if (s < SLOTS - 1)
                stage_tile(tile[(s + 1) & 1], tid, sbb[s + 1], sy0[s + 1], sx0[s + 1],
                           t, first, xp, h_rd);
            compute_slot(tile[s & 1], Wfrag, bg, abase,
                         sbb[s], sy0[s], sx0[s], lane, wave, u, quad,
                         creg[s], h_wr);
        }

        if (t != TT - 1) {
            __threadfence();   // release h_wr (cross-XCD)
            grid.sync();
            __threadfence();   // acquire before reading h from other XCDs
        }
    }
}

// Fallback: one step per launch (R4 path), c in global ws.
__global__ __launch_bounds__(256)
void convlstm_step_kernel(const unsigned short* __restrict__ xp, int t,
                          const unsigned short* __restrict__ h_in,
                          unsigned short* __restrict__ h_out,
                          float* __restrict__ c_state,
                          const unsigned short* __restrict__ Wfrag,
                          const float* __restrict__ bias,
                          int first) {
    __shared__ unsigned short tile[NPX * STRIDE];

    const int tid  = threadIdx.x;
    const int lane = tid & 63;
    const int wave = tid >> 6;
    const int u    = lane & 15;
    const int quad = lane >> 4;
    const int x0 = blockIdx.x * TX;
    const int y0 = blockIdx.y * TY;
    const int bb = blockIdx.z;

    float bg[4];
    #pragma unroll
    for (int g = 0; g < 4; ++g) bg[g] = bias[g * 16 + u];

    int abase[4];
    #pragma unroll
    for (int ml = 0; ml < 4; ++ml) {
        int m  = wave + ml * 4;
        int my = m >> 1;
        int mx = (m & 1) << 4;
        abase[ml] = (my * HALO_X + mx + u) * STRIDE + quad * 8;
    }

    stage_tile(tile, tid, bb, y0, x0, t, first, xp, h_in);
    __syncthreads();

    float creg[16];
    #pragma unroll
    for (int ml = 0; ml < 4; ++ml) {
        int m  = wave + ml * 4;
        int my = m >> 1;
        int mx = (m & 1) << 4;
        int py = y0 + my;
        #pragma unroll
        for (int r = 0; r < 4; ++r) {
            int pxx = x0 + mx + quad * 4 + r;
            size_t idx = ((size_t)bb * HH * WW + (size_t)py * WW + pxx) * HIDDEN + u;
            creg[ml * 4 + r] = first ? 0.0f : c_state[idx];
        }
    }

    compute_slot(tile, Wfrag, bg, abase, bb, y0, x0, lane, wave, u, quad,
                 creg, h_out);

    #pragma unroll
    for (int ml = 0; ml < 4; ++ml) {
        int m  = wave + ml * 4;
        int my = m >> 1;
        int mx = (m & 1) << 4;
        int py = y0 + my;
        #pragma unroll
        for (int r = 0; r < 4; ++r) {
            int pxx = x0 + mx + quad * 4 + r;
            size_t idx = ((size_t)bb * HH * WW + (size_t)py * WW + pxx) * HIDDEN + u;
            c_state[idx] = creg[ml * 4 + r];
        }
    }
}

// Final 1x1 conv from bf16 channel-last h
__global__ void final_conv_kernel(const unsigned short* __restrict__ h,
                                  const float* __restrict__ Wf,
                                  const float* __restrict__ bf_,
                                  float* __restrict__ out) {
    int i = blockIdx.x * 256 + threadIdx.x;
    if (i >= BB * HH * WW) return;
    size_t base = (size_t)i * HIDDEN;
    uint4 v0 = *(const uint4*)&h[base];
    uint4 v1 = *(const uint4*)&h[base + 8];
    const unsigned short* p0 = (const unsigned short*)&v0;
    const unsigned short* p1 = (const unsigned short*)&v1;
    float s = bf_[0];
    #pragma unroll
    for (int k = 0; k < 8; ++k) s += Wf[k] * bf2f(p0[k]);
    #pragma unroll
    for (int k = 0; k < 8; ++k) s += Wf[8 + k] * bf2f(p1[k]);
    out[i] = s;
}

extern "C" void kernel_launch(void* const* d_in, const int* in_sizes, int n_in,
                              void* d_out, int out_size, void* d_ws, size_t ws_size,
                              hipStream_t stream) {
    const float* x  = (const float*)d_in[0];
    const float* Wc = (const float*)d_in[1];
    const float* bc = (const float*)d_in[2];
    const float* Wf = (const float*)d_in[3];
    const float* bf = (const float*)d_in[4];
    float* out = (float*)d_out;

    char* ws = (char*)d_ws;
    const size_t h_bytes = (size_t)BB * HH * WW * HIDDEN * 2;   // 16.78 MB
    const size_t w_bytes = 64 * 1024;                           // Wfrag (36.9 KB used)
    const size_t x_bytes = (size_t)BB * TT * HH * WW * 8 * 2;   // 100.7 MB

    unsigned short* h_a = (unsigned short*)(ws);
    unsigned short* h_b = (unsigned short*)(ws + h_bytes);
    unsigned short* Wfr = (unsigned short*)(ws + 2 * h_bytes);
    unsigned short* xp  = (unsigned short*)(ws + 2 * h_bytes + w_bytes);
    float* c_fb         = (float*)(ws + 2 * h_bytes + w_bytes + x_bytes);
    (void)ws_size;

    prep_w_kernel<<<(9 * 4 * 64 * 8 + 255) / 256, 256, 0, stream>>>(Wc, Wfr);
    {
        size_t totpx = (size_t)BB * TT * HH * WW;
        prep_x_kernel<<<(int)((totpx + 255) / 256), 256, 0, stream>>>(x, xp);
    }

    void* args[] = {(void*)&xp, (void*)&h_a, (void*)&h_b, (void*)&Wfr, (void*)&bc};
    hipError_t cerr = hipLaunchCooperativeKernel(
        (void*)convlstm_persistent_kernel, dim3(NBLK), dim3(256), args, 0, stream);

    if (cerr != hipSuccess) {
        (void)hipGetLastError();   // clear error state
        dim3 grid(WW / TX, HH / TY, BB);
        dim3 block(256, 1, 1);
        const unsigned short* h_in = h_a;
        for (int t = 0; t < TT; ++t) {
            unsigned short* h_out = (t & 1) ? h_b : h_a;
            convlstm_step_kernel<<<grid, block, 0, stream>>>(
                xp, t, h_in, h_out, c_fb, Wfr, bc, (t == 0) ? 1 : 0);
            h_in = h_out;
        }
    }

    // TT=12 -> last write (t=11, odd) is h_b on both paths
    final_conv_kernel<<<(BB * HH * WW + 255) / 256, 256, 0, stream>>>(
        h_b, Wf, bf, out);
}

// Round 8
// 719.425 us; speedup vs baseline: 3.3311x; 3.3311x over previous
//
#include <hip/hip_runtime.h>
#include <math.h>

#define HIDDEN 16
#define CIN 5
#define BB 8
#define TT 12
#define HH 256
#define WW 256
#define TX 32
#define TY 8
#define HALO_X 34
#define HALO_Y 10
#define NPX (HALO_X * HALO_Y)   // 340 staged pixels
#define STRIDE 40               // shorts per px row: 80 B -> max 2-way bank aliasing (free)

typedef __attribute__((ext_vector_type(8))) short bf16x8;
typedef __attribute__((ext_vector_type(4))) float floatx4;

__device__ __forceinline__ unsigned short f2bf(float f) {   // RNE fp32->bf16
    unsigned int u = __float_as_uint(f);
    u += 0x7fffu + ((u >> 16) & 1u);
    return (unsigned short)(u >> 16);
}
__device__ __forceinline__ float bf2f(unsigned short s) {
    return __uint_as_float(((unsigned int)s) << 16);
}
__device__ __forceinline__ float fast_sigmoid(float x) { return 1.0f / (1.0f + __expf(-x)); }
__device__ __forceinline__ float fast_tanh(float x) {
    float e2 = __expf(-2.0f * fabsf(x));
    float t = (1.0f - e2) / (1.0f + e2);
    return copysignf(t, x);
}

// Pack W_cell [64][21][3][3] into B-fragment layout for mfma_f32_16x16x32_bf16:
// Wfrag[tap][gate][lane][j]; lane holds B[k=(lane>>4)*8+j][col=lane&15].
// k-order: 0..15 = h units (ci_ref 5+k), 16..20 = x chans, 21..31 = 0.
__global__ void prep_w_kernel(const float* __restrict__ Wc,
                              unsigned short* __restrict__ Wfrag) {
    int i = blockIdx.x * 256 + threadIdx.x;
    if (i >= 9 * 4 * 64 * 8) return;
    int j    = i & 7;
    int lane = (i >> 3) & 63;
    int g    = (i >> 9) & 3;
    int tap  = i >> 11;
    int k    = ((lane >> 4) << 3) + j;
    int col  = lane & 15;
    int o    = g * 16 + col;
    float w  = 0.0f;
    if (k < 21) {
        int ci_ref = (k < 16) ? (5 + k) : (k - 16);
        w = Wc[(o * 21 + ci_ref) * 9 + tap];
    }
    Wfrag[i] = f2bf(w);
}

// One-time x repack: planar fp32 [b][t][c][y][x] -> channel-last bf16 [b][t][y][x][8]
__global__ void prep_x_kernel(const float* __restrict__ x,
                              unsigned short* __restrict__ xp) {
    size_t n = (size_t)blockIdx.x * 256 + threadIdx.x;
    const size_t TOTPX = (size_t)BB * TT * HH * WW;
    if (n >= TOTPX) return;
    size_t bt  = n / (size_t)(HH * WW);
    size_t pix = n - bt * (size_t)(HH * WW);
    const float* src = x + bt * (size_t)CIN * HH * WW + pix;
    unsigned short v[8];
    #pragma unroll
    for (int c = 0; c < CIN; ++c) v[c] = f2bf(src[(size_t)c * HH * WW]);
    v[5] = 0; v[6] = 0; v[7] = 0;
    *(uint4*)&xp[n * 8] = *(const uint4*)v;
}

// One ConvLSTM step. Single-pass MFMA accumulation (acc in AGPRs),
// c-state in lane-contiguous layout [tile][wave][lane][16] (coalesced float4 io).
__global__ __launch_bounds__(256, 3)
void convlstm_step_kernel(const unsigned short* __restrict__ xp, int t,
                          const unsigned short* __restrict__ h_in,
                          unsigned short* __restrict__ h_out,
                          floatx4* __restrict__ c_ws,   // [2048][4][64][4] float4
                          const unsigned short* __restrict__ Wfrag,
                          const float* __restrict__ bias,
                          int first) {
    __shared__ unsigned short tile[NPX * STRIDE];   // 27.2 KB

    const int tid  = threadIdx.x;
    const int lane = tid & 63;
    const int wave = tid >> 6;
    const int u    = lane & 15;
    const int quad = lane >> 4;
    const int bx = blockIdx.x;          // 8 tile cols
    const int by = blockIdx.y;          // 32 tile rows
    const int bb = blockIdx.z;          // batch
    const int x0 = bx * TX;
    const int y0 = by * TY;
    const int tileid = (bb * 32 + by) * 8 + bx;

    // ---- stage tile: channel-last bf16, zero-padded halo & k-pad ----
    for (int i = tid; i < NPX; i += 256) {
        int ly = i / HALO_X;
        int lx = i - ly * HALO_X;
        int gy = y0 + ly - 1;
        int gx = x0 + lx - 1;
        bool inb = (gy >= 0 && gy < HH && gx >= 0 && gx < WW);
        unsigned short* row = &tile[i * STRIDE];
        uint4 z = {0, 0, 0, 0};
        if (inb && !first) {
            size_t hb = ((size_t)bb * HH * WW + (size_t)gy * WW + gx) * HIDDEN;
            *(uint4*)&row[0] = *(const uint4*)&h_in[hb];
            *(uint4*)&row[8] = *(const uint4*)&h_in[hb + 8];
        } else {
            *(uint4*)&row[0] = z;
            *(uint4*)&row[8] = z;
        }
        if (inb) {
            size_t xb = (((size_t)bb * TT + t) * (size_t)(HH * WW)
                         + (size_t)gy * WW + gx) * 8;
            *(uint4*)&row[16] = *(const uint4*)&xp[xb];
        } else {
            *(uint4*)&row[16] = z;
        }
        *(uint4*)&row[24] = z;
    }

    // ---- c-state load (coalesced, overlaps staging; independent of LDS) ----
    floatx4 cv[4];
    const size_t cbase = ((size_t)tileid * 4 + wave) * 64 + lane;   // in float4[4] units
    if (!first) {
        #pragma unroll
        for (int ml = 0; ml < 4; ++ml) cv[ml] = c_ws[cbase * 4 + ml];
    } else {
        #pragma unroll
        for (int ml = 0; ml < 4; ++ml) cv[ml] = (floatx4){0.f, 0.f, 0.f, 0.f};
    }

    float bg[4];
    #pragma unroll
    for (int g = 0; g < 4; ++g) bg[g] = bias[g * 16 + u];

    int abase[4];
    #pragma unroll
    for (int ml = 0; ml < 4; ++ml) {
        int m  = wave + ml * 4;
        int my = m >> 1;
        int mx = (m & 1) << 4;
        abase[ml] = (my * HALO_X + mx + u) * STRIDE + quad * 8;
    }

    __syncthreads();

    // ---- conv: single pass, 4 M-strips x 4 gates, acc in AGPRs ----
    floatx4 acc[4][4];
    #pragma unroll
    for (int ml = 0; ml < 4; ++ml)
        #pragma unroll
        for (int g = 0; g < 4; ++g)
            acc[ml][g] = (floatx4){bg[g], bg[g], bg[g], bg[g]};

    #pragma unroll
    for (int tap = 0; tap < 9; ++tap) {
        const int ky = tap / 3;
        const int kx = tap - ky * 3;
        const int toff = (ky * HALO_X + kx) * STRIDE;
        bf16x8 bfr[4];
        #pragma unroll
        for (int g = 0; g < 4; ++g)
            bfr[g] = *(const bf16x8*)&Wfrag[(size_t)((tap * 4 + g) * 64 + lane) * 8];
        bf16x8 af[4];
        #pragma unroll
        for (int ml = 0; ml < 4; ++ml)
            af[ml] = *(const bf16x8*)&tile[abase[ml] + toff];
        #pragma unroll
        for (int ml = 0; ml < 4; ++ml)
            #pragma unroll
            for (int g = 0; g < 4; ++g)
                acc[ml][g] = __builtin_amdgcn_mfma_f32_16x16x32_bf16(
                    af[ml], bfr[g], acc[ml][g], 0, 0, 0);
    }

    // ---- epilogue: gates + state update ----
    #pragma unroll
    for (int ml = 0; ml < 4; ++ml) {
        int m  = wave + ml * 4;
        int my = m >> 1;
        int mx = (m & 1) << 4;
        int py = y0 + my;
        #pragma unroll
        for (int r = 0; r < 4; ++r) {
            int pxx = x0 + mx + quad * 4 + r;
            size_t idx = ((size_t)bb * HH * WW + (size_t)py * WW + pxx) * HIDDEN + u;
            float ig = fast_sigmoid(acc[ml][0][r]);
            float fg = fast_sigmoid(acc[ml][1][r]);
            float og = fast_sigmoid(acc[ml][2][r]);
            float gg = fast_tanh(acc[ml][3][r]);
            float c_new = fg * cv[ml][r] + ig * gg;
            cv[ml][r] = c_new;
            h_out[idx] = f2bf(og * fast_tanh(c_new));
        }
    }

    // ---- c-state store (coalesced) ----
    #pragma unroll
    for (int ml = 0; ml < 4; ++ml) c_ws[cbase * 4 + ml] = cv[ml];
}

// Final 1x1 conv from bf16 channel-last h
__global__ void final_conv_kernel(const unsigned short* __restrict__ h,
                                  const float* __restrict__ Wf,
                                  const float* __restrict__ bf_,
                                  float* __restrict__ out) {
    int i = blockIdx.x * 256 + threadIdx.x;
    if (i >= BB * HH * WW) return;
    size_t base = (size_t)i * HIDDEN;
    uint4 v0 = *(const uint4*)&h[base];
    uint4 v1 = *(const uint4*)&h[base + 8];
    const unsigned short* p0 = (const unsigned short*)&v0;
    const unsigned short* p1 = (const unsigned short*)&v1;
    float s = bf_[0];
    #pragma unroll
    for (int k = 0; k < 8; ++k) s += Wf[k] * bf2f(p0[k]);
    #pragma unroll
    for (int k = 0; k < 8; ++k) s += Wf[8 + k] * bf2f(p1[k]);
    out[i] = s;
}

extern "C" void kernel_launch(void* const* d_in, const int* in_sizes, int n_in,
                              void* d_out, int out_size, void* d_ws, size_t ws_size,
                              hipStream_t stream) {
    const float* x  = (const float*)d_in[0];
    const float* Wc = (const float*)d_in[1];
    const float* bc = (const float*)d_in[2];
    const float* Wf = (const float*)d_in[3];
    const float* bf = (const float*)d_in[4];
    float* out = (float*)d_out;

    char* ws = (char*)d_ws;
    const size_t h_bytes = (size_t)BB * HH * WW * HIDDEN * 2;   // 16.78 MB
    const size_t w_bytes = 64 * 1024;                           // Wfrag (36.9 KB used)
    const size_t x_bytes = (size_t)BB * TT * HH * WW * 8 * 2;   // 100.7 MB

    unsigned short* h_a = (unsigned short*)(ws);
    unsigned short* h_b = (unsigned short*)(ws + h_bytes);
    unsigned short* Wfr = (unsigned short*)(ws + 2 * h_bytes);
    unsigned short* xp  = (unsigned short*)(ws + 2 * h_bytes + w_bytes);
    floatx4* c_ws       = (floatx4*)(ws + 2 * h_bytes + w_bytes + x_bytes); // 33.55 MB
    (void)ws_size;

    prep_w_kernel<<<(9 * 4 * 64 * 8 + 255) / 256, 256, 0, stream>>>(Wc, Wfr);
    {
        size_t totpx = (size_t)BB * TT * HH * WW;
        prep_x_kernel<<<(int)((totpx + 255) / 256), 256, 0, stream>>>(x, xp);
    }

    dim3 grid(WW / TX, HH / TY, BB);   // 8 x 32 x 8 = 2048 blocks
    dim3 block(256, 1, 1);

    const unsigned short* h_in = h_a;
    for (int t = 0; t < TT; ++t) {
        unsigned short* h_out = (t & 1) ? h_b : h_a;
        convlstm_step_kernel<<<grid, block, 0, stream>>>(
            xp, t, h_in, h_out, c_ws, Wfr, bc, (t == 0) ? 1 : 0);
        h_in = h_out;
    }

    // TT=12 -> last write (t=11, odd) went to h_b
    final_conv_kernel<<<(BB * HH * WW + 255) / 256, 256, 0, stream>>>(
        h_b, Wf, bf, out);
}